// Round 12
// baseline (197.439 us; speedup 1.0000x reference)
//
#include <hip/hip_runtime.h>
#include <math.h>

#define C 64
#define NHEADS 4
#define DH 16
#define NN 262144   // H*W
#define NB 2
#define PB 512      // partial Gram blocks per batch
#define NT 2        // 256-col tiles per block (gram)
#define EPS 1e-12f

typedef __attribute__((ext_vector_type(8))) short short8v;     // 8 bf16
typedef __attribute__((ext_vector_type(8))) unsigned short ushort8v;
typedef __attribute__((ext_vector_type(4))) float f32x4;

static __device__ __forceinline__ unsigned short f2bf(float f) {
  union { float f; unsigned int u; } v; v.f = f;
  unsigned int r = v.u + 0x7fffu + ((v.u >> 16) & 1u);   // RNE round to bf16
  return (unsigned short)(r >> 16);
}

static __device__ __forceinline__ short8v pack8(float4 v0, float4 v1) {
  ushort8v pk;
  pk[0] = f2bf(v0.x); pk[1] = f2bf(v0.y); pk[2] = f2bf(v0.z); pk[3] = f2bf(v0.w);
  pk[4] = f2bf(v1.x); pk[5] = f2bf(v1.y); pk[6] = f2bf(v1.z); pk[7] = f2bf(v1.w);
  return *reinterpret_cast<short8v*>(&pk);
}

// ---------------- K1: partial Grams — LDS-free, barrier-free (apply_B recipe) ----
// grid (PB, NB), 256 threads = 4 waves, launch_bounds(256,4) -> 16 waves/CU.
// For G = X X^T the MFMA k-dim IS n, so each lane's fragment is 8 CONSECUTIVE
// floats of one x row: 2 float4 loads/frag (16 segs x 128 B per instr).
// Per k-slot: phase-split {8 float4 loads -> pack bf16 -> 4 MFMAs}; no LDS,
// no barriers -> loads pipeline across slots/tiles; waves share rows via L1/L2.
__global__ __launch_bounds__(256, 4) void gram_kernel(const float* __restrict__ x,
                                                      float* __restrict__ Gc) {
  const int b = blockIdx.y;
  const int chunk = blockIdx.x;
  const float* xb = x + (size_t)b * C * NN;
  const int t = threadIdx.x;
  const int w = t >> 6, l = t & 63;
  const int lrow = l & 15, lhi = l >> 4;

  const int gA0 = (w >> 1) * 2, gA1 = gA0 + 1;
  const int gB0 = (w & 1) * 2,  gB1 = gB0 + 1;
  const float* rA0 = xb + (size_t)(gA0 * 16 + lrow) * NN;
  const float* rA1 = xb + (size_t)(gA1 * 16 + lrow) * NN;
  const float* rB0 = xb + (size_t)(gB0 * 16 + lrow) * NN;
  const float* rB1 = xb + (size_t)(gB1 * 16 + lrow) * NN;

  f32x4 acc0 = {0.f,0.f,0.f,0.f}, acc1 = {0.f,0.f,0.f,0.f};
  f32x4 acc2 = {0.f,0.f,0.f,0.f}, acc3 = {0.f,0.f,0.f,0.f};

#pragma unroll 1
  for (int tile = 0; tile < NT; ++tile) {
    const int j0 = (chunk * NT + tile) * 256;
#pragma unroll 2
    for (int s = 0; s < 8; ++s) {
      const int off = j0 + s * 32 + lhi * 8;   // this lane's 8-float k-span
      // ---- phase 1: 8 independent float4 loads ----
      const float4 a00 = *reinterpret_cast<const float4*>(rA0 + off);
      const float4 a01 = *reinterpret_cast<const float4*>(rA0 + off + 4);
      const float4 a10 = *reinterpret_cast<const float4*>(rA1 + off);
      const float4 a11 = *reinterpret_cast<const float4*>(rA1 + off + 4);
      const float4 b00 = *reinterpret_cast<const float4*>(rB0 + off);
      const float4 b01 = *reinterpret_cast<const float4*>(rB0 + off + 4);
      const float4 b10 = *reinterpret_cast<const float4*>(rB1 + off);
      const float4 b11 = *reinterpret_cast<const float4*>(rB1 + off + 4);
      // ---- phase 2: pack to bf16 ----
      const short8v fA0 = pack8(a00, a01);
      const short8v fA1 = pack8(a10, a11);
      const short8v fB0 = pack8(b00, b01);
      const short8v fB1 = pack8(b10, b11);
      // ---- phase 3: MFMA ----
      acc0 = __builtin_amdgcn_mfma_f32_16x16x32_bf16(fA0, fB0, acc0, 0, 0, 0);
      acc1 = __builtin_amdgcn_mfma_f32_16x16x32_bf16(fA0, fB1, acc1, 0, 0, 0);
      acc2 = __builtin_amdgcn_mfma_f32_16x16x32_bf16(fA1, fB0, acc2, 0, 0, 0);
      acc3 = __builtin_amdgcn_mfma_f32_16x16x32_bf16(fA1, fB1, acc3, 0, 0, 0);
    }
  }
  // C/D layout: col = lane&15, row = (lane>>4)*4 + reg
  float* g = Gc + ((size_t)b * PB + chunk) * 4096;
#pragma unroll
  for (int r = 0; r < 4; ++r) {
    const int row = lhi * 4 + r;
    g[(gA0 * 16 + row) * 64 + gB0 * 16 + lrow] = acc0[r];
    g[(gA0 * 16 + row) * 64 + gB1 * 16 + lrow] = acc1[r];
    g[(gA1 * 16 + row) * 64 + gB0 * 16 + lrow] = acc2[r];
    g[(gA1 * 16 + row) * 64 + gB1 * 16 + lrow] = acc3[r];
  }
}

// ---------------- K1b: tree-reduce the PB partials -> G[b][4096] ----------------
__global__ __launch_bounds__(256) void reduce_kernel(const float* __restrict__ Gc,
                                                     float* __restrict__ G) {
  __shared__ float s[4][64];
  const int b = blockIdx.y;
  const int g = blockIdx.x;
  const int t = threadIdx.x;
  const int e = g * 64 + (t & 63);
  const int chunk = t >> 6;
  float sum = 0.f;
  for (int p = chunk; p < PB; p += 4)
    sum += Gc[((size_t)b * PB + p) * 4096 + e];
  s[chunk][t & 63] = sum;
  __syncthreads();
  if (t < 64) G[(size_t)b * 4096 + g * 64 + t] = s[0][t] + s[1][t] + s[2][t] + s[3][t];
}

// ---------------- K2: attention math -> E (bf16, includes +I) ----------------
__global__ __launch_bounds__(256) void attn_kernel(const float* __restrict__ G,
    const float* __restrict__ Wq, const float* __restrict__ Wk,
    const float* __restrict__ Wv, const float* __restrict__ Wp,
    const float* __restrict__ rescale, unsigned short* __restrict__ Ebf) {
  __shared__ float Gs[4096], GQt[4096], GKt[4096], T[4096];
  __shared__ float attnw[64][DH];
  __shared__ float nq[64], nk[64];
  const int b = blockIdx.x;
  const int t = threadIdx.x;

  for (int i = t; i < 4096; i += 256) Gs[i] = G[(size_t)b * 4096 + i];
  __syncthreads();
  for (int i = t; i < 4096; i += 256) {
    const int c = i >> 6, e = i & 63;
    float sq_ = 0.f, sk_ = 0.f;
    for (int c2 = 0; c2 < 64; ++c2) {
      const float g = Gs[c * 64 + c2];
      sq_ += g * Wq[e * 64 + c2];
      sk_ += g * Wk[e * 64 + c2];
    }
    GQt[c * 64 + e] = sq_;
    GKt[c * 64 + e] = sk_;
  }
  __syncthreads();
  if (t < 64) {
    float s = 0.f;
    for (int c2 = 0; c2 < 64; ++c2) s += Wq[t * 64 + c2] * GQt[c2 * 64 + t];
    nq[t] = sqrtf(fmaxf(s, 0.f));
  } else if (t < 128) {
    const int d = t - 64;
    float s = 0.f;
    for (int c2 = 0; c2 < 64; ++c2) s += Wk[d * 64 + c2] * GKt[c2 * 64 + d];
    nk[d] = sqrtf(fmaxf(s, 0.f));
  }
  __syncthreads();
  if (t < 64) {
    const int h = t >> 4;
    const float rs = rescale[h];
    const float nkd = fmaxf(nk[t], EPS);
    float logits[DH];
    float mx = -1e30f;
    for (int ee = 0; ee < DH; ++ee) {
      const int e = h * DH + ee;
      float num = 0.f;
      for (int c2 = 0; c2 < 64; ++c2) num += Wk[t * 64 + c2] * GQt[c2 * 64 + e];
      const float l = num / (nkd * fmaxf(nq[e], EPS)) * rs;
      logits[ee] = l;
      mx = fmaxf(mx, l);
    }
    float sum = 0.f;
    for (int ee = 0; ee < DH; ++ee) { const float p = expf(logits[ee] - mx); logits[ee] = p; sum += p; }
    const float inv = 1.f / sum;
    for (int ee = 0; ee < DH; ++ee) attnw[t][ee] = logits[ee] * inv;
  }
  __syncthreads();
  for (int i = t; i < 4096; i += 256) {
    const int r = i >> 6, c = i & 63;
    const int h = r >> 4;
    float s = 0.f;
    for (int e = 0; e < DH; ++e) s += attnw[r][e] * Wv[(h * DH + e) * 64 + c];
    T[i] = s;
  }
  __syncthreads();
  for (int i = t; i < 4096; i += 256) {
    const int r = i >> 6, c = i & 63;
    float s = (r == c) ? 1.f : 0.f;
    for (int m = 0; m < 64; ++m) s += Wp[r * 64 + m] * T[m * 64 + c];
    Ebf[(size_t)b * 4096 + i] = f2bf(s);
  }
}

// ---------------- K3: out = E * x + bp — R10-measured apply_B ----------------
// grid (512, NB), 256 threads = 4 waves, launch_bounds(256,4), VGPR≈52, no LDS.
// R10 probe: 43 us/rep, hbm 59%, 203 MB/rep = algorithmic ideal.
__global__ __launch_bounds__(256, 4) void apply_B(const float* __restrict__ x,
    const unsigned short* __restrict__ Ebf, const float* __restrict__ bp,
    float* __restrict__ out) {
  const int b = blockIdx.y;
  const float* xb = x + (size_t)b * C * NN;
  float* ob = out + (size_t)b * C * NN;
  const int t = threadIdx.x;
  const int w = t >> 6, l = t & 63;
  const int lrow = l & 15, lhi = l >> 4;

  short8v ef[4][2];
  const unsigned short* eb = Ebf + (size_t)b * 4096;
#pragma unroll
  for (int ot = 0; ot < 4; ++ot)
#pragma unroll
    for (int ks = 0; ks < 2; ++ks)
      ef[ot][ks] = *reinterpret_cast<const short8v*>(eb + (ot * 16 + lrow) * 64 + ks * 32 + lhi * 8);

  float bias[4];
#pragma unroll
  for (int ot = 0; ot < 4; ++ot) bias[ot] = bp[ot * 16 + lrow];

  const int gw = blockIdx.x * 4 + w;     // 2048 waves/batch; 8192 chunks; 4 contiguous each

#pragma unroll 1
  for (int ci = 0; ci < 4; ++ci) {
    const int n0 = (gw * 4 + ci) * 32;
    // ---- phase 1: issue ALL 32 loads into registers ----
    float xv[32];
#pragma unroll
    for (int nn = 0; nn < 2; ++nn) {
      const int n = n0 + nn * 16 + lrow;
#pragma unroll
      for (int ks = 0; ks < 2; ++ks) {
        const float* src = xb + (size_t)(ks * 32 + lhi * 8) * NN + n;
#pragma unroll
        for (int j = 0; j < 8; ++j)
          xv[nn * 16 + ks * 8 + j] = src[(size_t)j * NN];
      }
    }
    // ---- phase 2: convert ----
    short8v xf[2][2];
#pragma unroll
    for (int nn = 0; nn < 2; ++nn)
#pragma unroll
      for (int ks = 0; ks < 2; ++ks) {
        ushort8v pk;
#pragma unroll
        for (int j = 0; j < 8; ++j) pk[j] = f2bf(xv[nn * 16 + ks * 8 + j]);
        xf[nn][ks] = *reinterpret_cast<short8v*>(&pk);
      }
    // ---- phase 3: MFMA ----
    f32x4 acc[4][2];
#pragma unroll
    for (int ot = 0; ot < 4; ++ot)
#pragma unroll
      for (int nn = 0; nn < 2; ++nn) acc[ot][nn] = (f32x4){0.f, 0.f, 0.f, 0.f};
#pragma unroll
    for (int nn = 0; nn < 2; ++nn)
#pragma unroll
      for (int ks = 0; ks < 2; ++ks)
#pragma unroll
        for (int ot = 0; ot < 4; ++ot)
          acc[ot][nn] = __builtin_amdgcn_mfma_f32_16x16x32_bf16(xf[nn][ks], ef[ot][ks], acc[ot][nn], 0, 0, 0);
    // ---- phase 4: store (D[n][o] -> float4 over consecutive n) ----
#pragma unroll
    for (int ot = 0; ot < 4; ++ot) {
      const int o = ot * 16 + lrow;
#pragma unroll
      for (int nn = 0; nn < 2; ++nn) {
        float4 o4;
        o4.x = acc[ot][nn][0] + bias[ot];
        o4.y = acc[ot][nn][1] + bias[ot];
        o4.z = acc[ot][nn][2] + bias[ot];
        o4.w = acc[ot][nn][3] + bias[ot];
        *reinterpret_cast<float4*>(&ob[(size_t)o * NN + n0 + nn * 16 + lhi * 4]) = o4;
      }
    }
  }
}

extern "C" void kernel_launch(void* const* d_in, const int* in_sizes, int n_in,
                              void* d_out, int out_size, void* d_ws, size_t ws_size,
                              hipStream_t stream) {
  const float* x       = (const float*)d_in[0];
  const float* Wq      = (const float*)d_in[1];
  const float* Wk      = (const float*)d_in[2];
  const float* Wv      = (const float*)d_in[3];
  const float* Wp      = (const float*)d_in[4];
  const float* bp      = (const float*)d_in[5];
  const float* rescale = (const float*)d_in[6];
  float* out = (float*)d_out;

  // Partial Grams in d_out (16.8 MB; reduce consumes them before apply
  // overwrites — stream-ordered). ws: G + E only.
  float* Gc = out;
  float* G  = (float*)d_ws;                                        // NB*4096 f32
  unsigned short* Ebf = (unsigned short*)(G + (size_t)NB * 4096);  // NB*4096 bf16

  gram_kernel<<<dim3(PB, NB), dim3(256), 0, stream>>>(x, Gc);
  reduce_kernel<<<dim3(64, NB), dim3(256), 0, stream>>>(Gc, G);
  attn_kernel<<<dim3(NB), dim3(256), 0, stream>>>(G, Wq, Wk, Wv, Wp, rescale, Ebf);
  apply_B<<<dim3(512, NB), dim3(256), 0, stream>>>(x, Ebf, bp, out);
}

// Round 13
// 158.045 us; speedup vs baseline: 1.2493x; 1.2493x over previous
//
#include <hip/hip_runtime.h>
#include <math.h>

#define C 64
#define NHEADS 4
#define DH 16
#define NN 262144   // H*W
#define NB 2
#define PB 512      // partial Gram blocks per batch
#define NT 2        // 256-col tiles per block (gram)
#define EPS 1e-12f

typedef __attribute__((ext_vector_type(8))) short short8v;     // 8 bf16
typedef __attribute__((ext_vector_type(8))) unsigned short ushort8v;
typedef __attribute__((ext_vector_type(4))) float f32x4;

static __device__ __forceinline__ unsigned short f2bf(float f) {
  union { float f; unsigned int u; } v; v.f = f;
  unsigned int r = v.u + 0x7fffu + ((v.u >> 16) & 1u);   // RNE round to bf16
  return (unsigned short)(r >> 16);
}

// ---------------- K1: partial Grams via MFMA — R5 LDS structure, 4 blocks/CU ----
// grid (PB, NB), 256 threads = 4 waves. Block covers NT*256 n-cols.
// LDS tile: bf16 [64][256], 16B slot s of row c stored at (s ^ (c&7)) ->
// staging writes and frag reads conflict-free. Each x byte enters the CU ONCE
// (R12 lesson: LDS-free re-read variant is L1-latency-bound at 80 us).
// (256,4): 4 resident blocks/CU hide each other's barrier drains (R12 lever).
__global__ __launch_bounds__(256, 4) void gram_kernel(const float* __restrict__ x,
                                                      float* __restrict__ Gc) {
  __shared__ unsigned short xs[C * 256];
  const int b = blockIdx.y;
  const int chunk = blockIdx.x;
  const float* xb = x + (size_t)b * C * NN;
  const int t = threadIdx.x;
  const int w = t >> 6, l = t & 63;
  const int lrow = l & 15, lhi = l >> 4;

  const int gA0 = (w >> 1) * 2, gA1 = gA0 + 1;
  const int gB0 = (w & 1) * 2,  gB1 = gB0 + 1;
  const int cA0 = gA0 * 16 + lrow, cA1 = gA1 * 16 + lrow;
  const int cB0 = gB0 * 16 + lrow, cB1 = gB1 * 16 + lrow;

  f32x4 acc0 = {0.f,0.f,0.f,0.f}, acc1 = {0.f,0.f,0.f,0.f};
  f32x4 acc2 = {0.f,0.f,0.f,0.f}, acc3 = {0.f,0.f,0.f,0.f};

  for (int tile = 0; tile < NT; ++tile) {
    const int j0 = (chunk * NT + tile) * 256;
    __syncthreads();
#pragma unroll
    for (int i = 0; i < 8; ++i) {
      const int oi = i * 256 + t;
      const int c = oi >> 5, oct = oi & 31;          // 32 octets (8 bf16) per row
      const float* src = xb + (size_t)c * NN + j0 + oct * 8;
      const float4 v0 = *reinterpret_cast<const float4*>(src);
      const float4 v1 = *reinterpret_cast<const float4*>(src + 4);
      ushort8v pk;
      pk[0] = f2bf(v0.x); pk[1] = f2bf(v0.y); pk[2] = f2bf(v0.z); pk[3] = f2bf(v0.w);
      pk[4] = f2bf(v1.x); pk[5] = f2bf(v1.y); pk[6] = f2bf(v1.z); pk[7] = f2bf(v1.w);
      *reinterpret_cast<ushort8v*>(&xs[c * 256 + ((oct ^ (c & 7)) << 3)]) = pk;
    }
    __syncthreads();
#pragma unroll
    for (int s = 0; s < 8; ++s) {
      const int o = s * 4 + lhi;                     // 16B slot holding k=s*32+lhi*8..+7
      const short8v fA0 = *reinterpret_cast<const short8v*>(&xs[cA0 * 256 + ((o ^ (cA0 & 7)) << 3)]);
      const short8v fA1 = *reinterpret_cast<const short8v*>(&xs[cA1 * 256 + ((o ^ (cA1 & 7)) << 3)]);
      const short8v fB0 = *reinterpret_cast<const short8v*>(&xs[cB0 * 256 + ((o ^ (cB0 & 7)) << 3)]);
      const short8v fB1 = *reinterpret_cast<const short8v*>(&xs[cB1 * 256 + ((o ^ (cB1 & 7)) << 3)]);
      acc0 = __builtin_amdgcn_mfma_f32_16x16x32_bf16(fA0, fB0, acc0, 0, 0, 0);
      acc1 = __builtin_amdgcn_mfma_f32_16x16x32_bf16(fA0, fB1, acc1, 0, 0, 0);
      acc2 = __builtin_amdgcn_mfma_f32_16x16x32_bf16(fA1, fB0, acc2, 0, 0, 0);
      acc3 = __builtin_amdgcn_mfma_f32_16x16x32_bf16(fA1, fB1, acc3, 0, 0, 0);
    }
  }
  // C/D layout: col = lane&15, row = (lane>>4)*4 + reg
  float* g = Gc + ((size_t)b * PB + chunk) * 4096;
#pragma unroll
  for (int r = 0; r < 4; ++r) {
    const int row = lhi * 4 + r;
    g[(gA0 * 16 + row) * 64 + gB0 * 16 + lrow] = acc0[r];
    g[(gA0 * 16 + row) * 64 + gB1 * 16 + lrow] = acc1[r];
    g[(gA1 * 16 + row) * 64 + gB0 * 16 + lrow] = acc2[r];
    g[(gA1 * 16 + row) * 64 + gB1 * 16 + lrow] = acc3[r];
  }
}

// ---------------- K1b: tree-reduce the PB partials -> G[b][4096] ----------------
__global__ __launch_bounds__(256) void reduce_kernel(const float* __restrict__ Gc,
                                                     float* __restrict__ G) {
  __shared__ float s[4][64];
  const int b = blockIdx.y;
  const int g = blockIdx.x;
  const int t = threadIdx.x;
  const int e = g * 64 + (t & 63);
  const int chunk = t >> 6;
  float sum = 0.f;
  for (int p = chunk; p < PB; p += 4)
    sum += Gc[((size_t)b * PB + p) * 4096 + e];
  s[chunk][t & 63] = sum;
  __syncthreads();
  if (t < 64) G[(size_t)b * 4096 + g * 64 + t] = s[0][t] + s[1][t] + s[2][t] + s[3][t];
}

// ---------------- K2: attention math -> E (bf16, includes +I) ----------------
__global__ __launch_bounds__(256) void attn_kernel(const float* __restrict__ G,
    const float* __restrict__ Wq, const float* __restrict__ Wk,
    const float* __restrict__ Wv, const float* __restrict__ Wp,
    const float* __restrict__ rescale, unsigned short* __restrict__ Ebf) {
  __shared__ float Gs[4096], GQt[4096], GKt[4096], T[4096];
  __shared__ float attnw[64][DH];
  __shared__ float nq[64], nk[64];
  const int b = blockIdx.x;
  const int t = threadIdx.x;

  for (int i = t; i < 4096; i += 256) Gs[i] = G[(size_t)b * 4096 + i];
  __syncthreads();
  for (int i = t; i < 4096; i += 256) {
    const int c = i >> 6, e = i & 63;
    float sq_ = 0.f, sk_ = 0.f;
    for (int c2 = 0; c2 < 64; ++c2) {
      const float g = Gs[c * 64 + c2];
      sq_ += g * Wq[e * 64 + c2];
      sk_ += g * Wk[e * 64 + c2];
    }
    GQt[c * 64 + e] = sq_;
    GKt[c * 64 + e] = sk_;
  }
  __syncthreads();
  if (t < 64) {
    float s = 0.f;
    for (int c2 = 0; c2 < 64; ++c2) s += Wq[t * 64 + c2] * GQt[c2 * 64 + t];
    nq[t] = sqrtf(fmaxf(s, 0.f));
  } else if (t < 128) {
    const int d = t - 64;
    float s = 0.f;
    for (int c2 = 0; c2 < 64; ++c2) s += Wk[d * 64 + c2] * GKt[c2 * 64 + d];
    nk[d] = sqrtf(fmaxf(s, 0.f));
  }
  __syncthreads();
  if (t < 64) {
    const int h = t >> 4;
    const float rs = rescale[h];
    const float nkd = fmaxf(nk[t], EPS);
    float logits[DH];
    float mx = -1e30f;
    for (int ee = 0; ee < DH; ++ee) {
      const int e = h * DH + ee;
      float num = 0.f;
      for (int c2 = 0; c2 < 64; ++c2) num += Wk[t * 64 + c2] * GQt[c2 * 64 + e];
      const float l = num / (nkd * fmaxf(nq[e], EPS)) * rs;
      logits[ee] = l;
      mx = fmaxf(mx, l);
    }
    float sum = 0.f;
    for (int ee = 0; ee < DH; ++ee) { const float p = expf(logits[ee] - mx); logits[ee] = p; sum += p; }
    const float inv = 1.f / sum;
    for (int ee = 0; ee < DH; ++ee) attnw[t][ee] = logits[ee] * inv;
  }
  __syncthreads();
  for (int i = t; i < 4096; i += 256) {
    const int r = i >> 6, c = i & 63;
    const int h = r >> 4;
    float s = 0.f;
    for (int e = 0; e < DH; ++e) s += attnw[r][e] * Wv[(h * DH + e) * 64 + c];
    T[i] = s;
  }
  __syncthreads();
  for (int i = t; i < 4096; i += 256) {
    const int r = i >> 6, c = i & 63;
    float s = (r == c) ? 1.f : 0.f;
    for (int m = 0; m < 64; ++m) s += Wp[r * 64 + m] * T[m * 64 + c];
    Ebf[(size_t)b * 4096 + i] = f2bf(s);
  }
}

// ---------------- K3: out = E * x + bp — R10-measured apply_B ----------------
// grid (512, NB), 256 threads = 4 waves, launch_bounds(256,4), VGPR≈52, no LDS.
// R10 probe: 43 us/rep, hbm 59%, 203 MB/rep = algorithmic ideal.
__global__ __launch_bounds__(256, 4) void apply_B(const float* __restrict__ x,
    const unsigned short* __restrict__ Ebf, const float* __restrict__ bp,
    float* __restrict__ out) {
  const int b = blockIdx.y;
  const float* xb = x + (size_t)b * C * NN;
  float* ob = out + (size_t)b * C * NN;
  const int t = threadIdx.x;
  const int w = t >> 6, l = t & 63;
  const int lrow = l & 15, lhi = l >> 4;

  short8v ef[4][2];
  const unsigned short* eb = Ebf + (size_t)b * 4096;
#pragma unroll
  for (int ot = 0; ot < 4; ++ot)
#pragma unroll
    for (int ks = 0; ks < 2; ++ks)
      ef[ot][ks] = *reinterpret_cast<const short8v*>(eb + (ot * 16 + lrow) * 64 + ks * 32 + lhi * 8);

  float bias[4];
#pragma unroll
  for (int ot = 0; ot < 4; ++ot) bias[ot] = bp[ot * 16 + lrow];

  const int gw = blockIdx.x * 4 + w;     // 2048 waves/batch; 8192 chunks; 4 contiguous each

#pragma unroll 1
  for (int ci = 0; ci < 4; ++ci) {
    const int n0 = (gw * 4 + ci) * 32;
    // ---- phase 1: issue ALL 32 loads into registers ----
    float xv[32];
#pragma unroll
    for (int nn = 0; nn < 2; ++nn) {
      const int n = n0 + nn * 16 + lrow;
#pragma unroll
      for (int ks = 0; ks < 2; ++ks) {
        const float* src = xb + (size_t)(ks * 32 + lhi * 8) * NN + n;
#pragma unroll
        for (int j = 0; j < 8; ++j)
          xv[nn * 16 + ks * 8 + j] = src[(size_t)j * NN];
      }
    }
    // ---- phase 2: convert ----
    short8v xf[2][2];
#pragma unroll
    for (int nn = 0; nn < 2; ++nn)
#pragma unroll
      for (int ks = 0; ks < 2; ++ks) {
        ushort8v pk;
#pragma unroll
        for (int j = 0; j < 8; ++j) pk[j] = f2bf(xv[nn * 16 + ks * 8 + j]);
        xf[nn][ks] = *reinterpret_cast<short8v*>(&pk);
      }
    // ---- phase 3: MFMA ----
    f32x4 acc[4][2];
#pragma unroll
    for (int ot = 0; ot < 4; ++ot)
#pragma unroll
      for (int nn = 0; nn < 2; ++nn) acc[ot][nn] = (f32x4){0.f, 0.f, 0.f, 0.f};
#pragma unroll
    for (int nn = 0; nn < 2; ++nn)
#pragma unroll
      for (int ks = 0; ks < 2; ++ks)
#pragma unroll
        for (int ot = 0; ot < 4; ++ot)
          acc[ot][nn] = __builtin_amdgcn_mfma_f32_16x16x32_bf16(xf[nn][ks], ef[ot][ks], acc[ot][nn], 0, 0, 0);
    // ---- phase 4: store (D[n][o] -> float4 over consecutive n) ----
#pragma unroll
    for (int ot = 0; ot < 4; ++ot) {
      const int o = ot * 16 + lrow;
#pragma unroll
      for (int nn = 0; nn < 2; ++nn) {
        float4 o4;
        o4.x = acc[ot][nn][0] + bias[ot];
        o4.y = acc[ot][nn][1] + bias[ot];
        o4.z = acc[ot][nn][2] + bias[ot];
        o4.w = acc[ot][nn][3] + bias[ot];
        *reinterpret_cast<float4*>(&ob[(size_t)o * NN + n0 + nn * 16 + lhi * 4]) = o4;
      }
    }
  }
}

extern "C" void kernel_launch(void* const* d_in, const int* in_sizes, int n_in,
                              void* d_out, int out_size, void* d_ws, size_t ws_size,
                              hipStream_t stream) {
  const float* x       = (const float*)d_in[0];
  const float* Wq      = (const float*)d_in[1];
  const float* Wk      = (const float*)d_in[2];
  const float* Wv      = (const float*)d_in[3];
  const float* Wp      = (const float*)d_in[4];
  const float* bp      = (const float*)d_in[5];
  const float* rescale = (const float*)d_in[6];
  float* out = (float*)d_out;

  // Partial Grams in d_out (16.8 MB; reduce consumes them before apply
  // overwrites — stream-ordered). ws: G + E only.
  float* Gc = out;
  float* G  = (float*)d_ws;                                        // NB*4096 f32
  unsigned short* Ebf = (unsigned short*)(G + (size_t)NB * 4096);  // NB*4096 bf16

  gram_kernel<<<dim3(PB, NB), dim3(256), 0, stream>>>(x, Gc);
  reduce_kernel<<<dim3(64, NB), dim3(256), 0, stream>>>(Gc, G);
  attn_kernel<<<dim3(NB), dim3(256), 0, stream>>>(G, Wq, Wk, Wv, Wp, rescale, Ebf);
  apply_B<<<dim3(512, NB), dim3(256), 0, stream>>>(x, Ebf, bp, out);
}